// Round 8
// baseline (50.777 us; speedup 1.0000x reference)
//
#include <hip/hip_runtime.h>
#include <math.h>

#define NCAMS 6
#define CCH   32
#define YY    8
#define XX    256
#define ZZ    256
#define NVOX  (YY*XX*ZZ)        // 524288
#define IMG_H 224
#define IMG_W 400
#define FXV   56
#define FZV   100

#define NF (NCAMS*FXV*FZV)          // 33600 feat pixels
#define NV (NCAMS*IMG_H*IMG_W)      // 537600 vd pixels
#define FEATS_T_ELEMS (NF*CCH)      // 1,075,200
#define VD_T_ELEMS    (NV*2)        // 1,075,200
#define WS_NEED_BYTES ((size_t)(FEATS_T_ELEMS + VD_T_ELEMS) * 4)

// ---------------- fused prep: feats [6,32,56,100]->[6,56,100,32]; var+dep -> [6,224,400,2]
__global__ __launch_bounds__(256) void prep_all(
    const float* __restrict__ src_f, const float* __restrict__ var,
    const float* __restrict__ dep, float* __restrict__ dst_f,
    float* __restrict__ dst_vd)
{
    int t = blockIdx.x * 256 + threadIdx.x;
    if (t < NF) {
        int b = t / (FXV * FZV);
        int r = t - b * (FXV * FZV);
        float4* d4 = (float4*)(dst_f + (size_t)t * CCH);
        #pragma unroll
        for (int j = 0; j < CCH / 4; j++) {
            float4 v;
            v.x = src_f[(size_t)(b * CCH + 4*j + 0) * (FXV*FZV) + r];
            v.y = src_f[(size_t)(b * CCH + 4*j + 1) * (FXV*FZV) + r];
            v.z = src_f[(size_t)(b * CCH + 4*j + 2) * (FXV*FZV) + r];
            v.w = src_f[(size_t)(b * CCH + 4*j + 3) * (FXV*FZV) + r];
            d4[j] = v;
        }
    } else {
        int u = t - NF;
        if (u < NV) ((float2*)dst_vd)[u] = make_float2(var[u], dep[u]);
    }
}

// ---- main: 256-thread blocks = 4 independent waves, wave = 64 voxels.
//      Phase1 lane=voxel (project+vd+aux). Phase2: 4 sub-rounds x 16 voxels,
//      4 lanes/voxel x 8 channels; DIRECT full-line stores (no LDS transpose).
__global__ __launch_bounds__(256, 6) void mvmap_fast(
    const float* __restrict__ feats_t,   // [6,56,100,32]
    const float* __restrict__ vd_t,      // [6,224,400,2]
    const float* __restrict__ coords,    // [1,524288,3]  (px, pz, h)
    const float* __restrict__ Ps,        // [6,4,4] cam2world
    const float* __restrict__ Ks,        // [6,3,3]
    float* __restrict__ out)
{
    __shared__ float4 sW2C[NCAMS][3];   // rows [i0 i1 i2 | t]
    __shared__ float4 sK[NCAMS][3];     // rows of K (w unused)

    if (threadIdx.x < NCAMS) {
        int b = threadIdx.x;
        const float* P = Ps + b * 16;
        float r00=P[0], r01=P[1], r02=P[2],  tx=P[3];
        float r10=P[4], r11=P[5], r12=P[6],  ty=P[7];
        float r20=P[8], r21=P[9], r22=P[10], tz=P[11];
        float det = r00*(r11*r22 - r12*r21)
                  - r01*(r10*r22 - r12*r20)
                  + r02*(r10*r21 - r11*r20);
        float id = 1.0f / det;
        float i00 =  (r11*r22 - r12*r21) * id;
        float i01 = -(r01*r22 - r02*r21) * id;
        float i02 =  (r01*r12 - r02*r11) * id;
        float i10 = -(r10*r22 - r12*r20) * id;
        float i11 =  (r00*r22 - r02*r20) * id;
        float i12 = -(r00*r12 - r02*r10) * id;
        float i20 =  (r10*r21 - r11*r20) * id;
        float i21 = -(r00*r21 - r01*r20) * id;
        float i22 =  (r00*r11 - r01*r10) * id;
        sW2C[b][0] = make_float4(i00, i01, i02, -(i00*tx + i01*ty + i02*tz));
        sW2C[b][1] = make_float4(i10, i11, i12, -(i10*tx + i11*ty + i12*tz));
        sW2C[b][2] = make_float4(i20, i21, i22, -(i20*tx + i21*ty + i22*tz));
        sK[b][0] = make_float4(Ks[b*9+0], Ks[b*9+1], Ks[b*9+2], 0.f);
        sK[b][1] = make_float4(Ks[b*9+3], Ks[b*9+4], Ks[b*9+5], 0.f);
        sK[b][2] = make_float4(Ks[b*9+6], Ks[b*9+7], Ks[b*9+8], 0.f);
    }
    __syncthreads();

    int wv   = threadIdx.x >> 6;             // wave within block (0..3)
    int lane = threadIdx.x & 63;             // lane within wave
    int n0   = blockIdx.x * 256 + wv * 64;   // wave's 64-voxel base
    int n    = n0 + lane;                    // this lane's voxel

    float px = coords[3*n + 0];
    float pz = coords[3*n + 1];
    float ph = coords[3*n + 2];

    // ---------------- phase 1: projection + mask, compact into slots (lane = voxel)
    float wsum = 0.0f, zsum = 0.0f;
    int   nvis = 0;
    float s_u[3] = {0.f, 0.f, 0.f};
    float s_v[3] = {0.f, 0.f, 0.f};
    int   s_b[3] = {0, 0, 0};

    #pragma unroll
    for (int b = 0; b < NCAMS; b++) {
        float4 r0 = sW2C[b][0], r1 = sW2C[b][1], r2 = sW2C[b][2];
        float cx = r0.x*px + r0.y*pz + r0.z*ph + r0.w;
        float cy = r1.x*px + r1.y*pz + r1.z*ph + r1.w;
        float cz = r2.x*px + r2.y*pz + r2.z*ph + r2.w;
        float4 k0 = sK[b][0], k1 = sK[b][1], k2 = sK[b][2];
        float u0 = k0.x*cx + k0.y*cy + k0.z*cz;
        float v0 = k1.x*cx + k1.y*cy + k1.z*cz;
        float zc = k2.x*cx + k2.y*cy + k2.z*cz;
        float zsafe = (fabsf(zc) < 1e-6f) ? 1e-6f : zc;
        float u = u0 / zsafe;                 // exact IEEE divide (mask bit-identity)
        float v = v0 / zsafe;
        bool mask = (zc > 1e-3f) && (u >= 0.0f) && (u < (float)IMG_W)
                                 && (v >= 0.0f) && (v < (float)IMG_H);
        wsum += mask ? 1.0f : 0.0f;
        zsum += mask ? zc : 0.0f;
        bool c0 = mask && (nvis == 0);
        bool c1 = mask && (nvis == 1);
        bool c2 = mask && (nvis == 2);        // geometrically dead (HFOV 77 < 120), defensive
        s_u[0] = c0 ? u : s_u[0];  s_v[0] = c0 ? v : s_v[0];  s_b[0] = c0 ? b : s_b[0];
        s_u[1] = c1 ? u : s_u[1];  s_v[1] = c1 ? v : s_v[1];  s_b[1] = c1 ? b : s_b[1];
        s_u[2] = c2 ? u : s_u[2];  s_v[2] = c2 ? v : s_v[2];  s_b[2] = c2 ? b : s_b[2];
        nvis += mask ? 1 : 0;
    }
    float invd = 1.0f / (wsum + 1e-6f);

    // ---------------- phase 1b: variance + depth bilinear (lane = voxel)
    float vsum = 0.0f, ndsum = 0.0f;
    #pragma unroll
    for (int it = 0; it < 3; it++) {
        if (it < nvis) {
            float u = s_u[it], v = s_v[it];
            int   b = s_b[it];
            float xf = v - 0.5f;
            float yf = u - 0.5f;
            float x0f = floorf(xf), y0f = floorf(yf);
            float wx = xf - x0f, wy = yf - y0f;
            int x0 = (int)x0f, y0 = (int)y0f;
            float vx0 = (x0   >= 0 && x0   < IMG_H) ? 1.0f : 0.0f;
            float vx1 = (x0+1 >= 0 && x0+1 < IMG_H) ? 1.0f : 0.0f;
            float vy0 = (y0   >= 0 && y0   < IMG_W) ? 1.0f : 0.0f;
            float vy1 = (y0+1 >= 0 && y0+1 < IMG_W) ? 1.0f : 0.0f;
            float w00 = (1.0f-wx)*(1.0f-wy)*vx0*vy0;
            float w10 = wx*(1.0f-wy)*vx1*vy0;
            float w01 = (1.0f-wx)*wy*vx0*vy1;
            float w11 = wx*wy*vx1*vy1;
            int xi0 = min(max(x0,   0), IMG_H-1), xi1 = min(max(x0+1, 0), IMG_H-1);
            int yi0 = min(max(y0,   0), IMG_W-1), yi1 = min(max(y0+1, 0), IMG_W-1);
            const float2* pv = (const float2*)(vd_t) + (size_t)b * (IMG_H*IMG_W);
            float2 t00 = pv[xi0*IMG_W + yi0], t01 = pv[xi0*IMG_W + yi1];
            float2 t10 = pv[xi1*IMG_W + yi0], t11 = pv[xi1*IMG_W + yi1];
            vsum  += w00*t00.x + w01*t01.x + w10*t10.x + w11*t11.x;
            ndsum += w00*t00.y + w01*t01.y + w10*t10.y + w11*t11.y;
        }
    }
    __builtin_nontemporal_store(vsum  * invd, &out[(size_t)CCH*NVOX + n]);
    __builtin_nontemporal_store(zsum  * invd, &out[(size_t)CCH*NVOX + NVOX + n]);
    __builtin_nontemporal_store(ndsum * invd, &out[(size_t)CCH*NVOX + 2*(size_t)NVOX + n]);

    // ---------------- phase 2: 4 sub-rounds x 16 voxels; 4 lanes/voxel x 8 channels
    int cg = lane >> 4;       // channel quarter: channels 8*cg .. 8*cg+7
    int vg = lane & 15;       // voxel offset within sub-round

    #pragma unroll
    for (int s = 0; s < 4; s++) {
        int src = 16*s + vg;                // lane owning this voxel's projection

        // ---- HOISTED broadcasts: executed by ALL lanes (defined behavior) ----
        int   nv  = __shfl(nvis, src);
        float iv  = __shfl(invd, src);
        float uu0 = __shfl(s_u[0], src), vv0 = __shfl(s_v[0], src);
        float uu1 = __shfl(s_u[1], src), vv1 = __shfl(s_v[1], src);
        float uu2 = __shfl(s_u[2], src), vv2 = __shfl(s_v[2], src);
        int   bb0 = __shfl(s_b[0], src);
        int   bb1 = __shfl(s_b[1], src);
        int   bb2 = __shfl(s_b[2], src);
        float uu[3] = {uu0, uu1, uu2};
        float vv[3] = {vv0, vv1, vv2};
        int   bb[3] = {bb0, bb1, bb2};

        float4 f0 = make_float4(0.f,0.f,0.f,0.f);
        float4 f1 = make_float4(0.f,0.f,0.f,0.f);
        #pragma unroll
        for (int it = 0; it < 3; it++) {
            if (it < nv) {
                float u = uu[it], v = vv[it];
                int   b = bb[it];
                float xf = v * 0.25f - 0.5f;      // width dim (56)
                float yf = u * 0.25f - 0.5f;      // height dim (100)
                float x0f = floorf(xf), y0f = floorf(yf);
                float wx = xf - x0f, wy = yf - y0f;
                int x0 = (int)x0f, y0 = (int)y0f;
                float vx0 = (x0   >= 0 && x0   < FXV) ? 1.0f : 0.0f;
                float vx1 = (x0+1 >= 0 && x0+1 < FXV) ? 1.0f : 0.0f;
                float vy0 = (y0   >= 0 && y0   < FZV) ? 1.0f : 0.0f;
                float vy1 = (y0+1 >= 0 && y0+1 < FZV) ? 1.0f : 0.0f;
                float w00 = (1.0f-wx)*(1.0f-wy)*vx0*vy0;
                float w10 = wx*(1.0f-wy)*vx1*vy0;
                float w01 = (1.0f-wx)*wy*vx0*vy1;
                float w11 = wx*wy*vx1*vy1;
                int xi0 = min(max(x0,   0), FXV-1), xi1 = min(max(x0+1, 0), FXV-1);
                int yi0 = min(max(y0,   0), FZV-1), yi1 = min(max(y0+1, 0), FZV-1);
                const float* base = feats_t + (size_t)b * (FXV*FZV*CCH) + cg * 8;
                const float4* p00 = (const float4*)(base + (size_t)(xi0*FZV + yi0)*CCH);
                const float4* p01 = (const float4*)(base + (size_t)(xi0*FZV + yi1)*CCH);
                const float4* p10 = (const float4*)(base + (size_t)(xi1*FZV + yi0)*CCH);
                const float4* p11 = (const float4*)(base + (size_t)(xi1*FZV + yi1)*CCH);
                {
                    float4 a = p00[0], b2 = p01[0], c2 = p10[0], d2 = p11[0];
                    f0.x += w00*a.x + w01*b2.x + w10*c2.x + w11*d2.x;
                    f0.y += w00*a.y + w01*b2.y + w10*c2.y + w11*d2.y;
                    f0.z += w00*a.z + w01*b2.z + w10*c2.z + w11*d2.z;
                    f0.w += w00*a.w + w01*b2.w + w10*c2.w + w11*d2.w;
                }
                {
                    float4 a = p00[1], b2 = p01[1], c2 = p10[1], d2 = p11[1];
                    f1.x += w00*a.x + w01*b2.x + w10*c2.x + w11*d2.x;
                    f1.y += w00*a.y + w01*b2.y + w10*c2.y + w11*d2.y;
                    f1.z += w00*a.z + w01*b2.z + w10*c2.z + w11*d2.z;
                    f1.w += w00*a.w + w01*b2.w + w10*c2.w + w11*d2.w;
                }
            }
        }
        // ---- direct stores: channel 8*cg+k, 16 consecutive lanes -> 64B full lines
        int vn = n0 + 16*s + vg;
        #pragma unroll
        for (int k = 0; k < 4; k++) {
            __builtin_nontemporal_store((&f0.x)[k] * iv, &out[(size_t)(8*cg + k) * NVOX + vn]);
        }
        #pragma unroll
        for (int k = 0; k < 4; k++) {
            __builtin_nontemporal_store((&f1.x)[k] * iv, &out[(size_t)(8*cg + 4 + k) * NVOX + vn]);
        }
    }
}

// ---------------- fallback (original layouts, one thread per voxel) --------------
__global__ __launch_bounds__(256) void mvmap_main(
    const float* __restrict__ img_feats,
    const float* __restrict__ variances,
    const float* __restrict__ render_depth,
    const float* __restrict__ coords,
    const float* __restrict__ Ps,
    const float* __restrict__ Ks,
    float* __restrict__ out)
{
    __shared__ float sW2C[NCAMS][12];
    __shared__ float sK[NCAMS][9];

    if (threadIdx.x < NCAMS) {
        int b = threadIdx.x;
        const float* P = Ps + b * 16;
        float r00=P[0], r01=P[1], r02=P[2],  tx=P[3];
        float r10=P[4], r11=P[5], r12=P[6],  ty=P[7];
        float r20=P[8], r21=P[9], r22=P[10], tz=P[11];
        float det = r00*(r11*r22 - r12*r21)
                  - r01*(r10*r22 - r12*r20)
                  + r02*(r10*r21 - r11*r20);
        float id = 1.0f / det;
        float i00 =  (r11*r22 - r12*r21) * id;
        float i01 = -(r01*r22 - r02*r21) * id;
        float i02 =  (r01*r12 - r02*r11) * id;
        float i10 = -(r10*r22 - r12*r20) * id;
        float i11 =  (r00*r22 - r02*r20) * id;
        float i12 = -(r00*r12 - r02*r10) * id;
        float i20 =  (r10*r21 - r11*r20) * id;
        float i21 = -(r00*r21 - r01*r20) * id;
        float i22 =  (r00*r11 - r01*r10) * id;
        sW2C[b][0]=i00; sW2C[b][1]=i01; sW2C[b][2] =i02; sW2C[b][3] =-(i00*tx + i01*ty + i02*tz);
        sW2C[b][4]=i10; sW2C[b][5]=i11; sW2C[b][6] =i12; sW2C[b][7] =-(i10*tx + i11*ty + i12*tz);
        sW2C[b][8]=i20; sW2C[b][9]=i21; sW2C[b][10]=i22; sW2C[b][11]=-(i20*tx + i21*ty + i22*tz);
        #pragma unroll
        for (int jj = 0; jj < 9; jj++) sK[b][jj] = Ks[b*9 + jj];
    }
    __syncthreads();

    int n = blockIdx.x * blockDim.x + threadIdx.x;
    if (n >= NVOX) return;

    float px = coords[3*n + 0];
    float pz = coords[3*n + 1];
    float ph = coords[3*n + 2];

    float fsum[CCH];
    #pragma unroll
    for (int c = 0; c < CCH; c++) fsum[c] = 0.0f;
    float wsum = 0.0f, vsum = 0.0f, ndsum = 0.0f, zsum = 0.0f;

    for (int b = 0; b < NCAMS; b++) {
        float cx = sW2C[b][0]*px + sW2C[b][1]*pz + sW2C[b][2] *ph + sW2C[b][3];
        float cy = sW2C[b][4]*px + sW2C[b][5]*pz + sW2C[b][6] *ph + sW2C[b][7];
        float cz = sW2C[b][8]*px + sW2C[b][9]*pz + sW2C[b][10]*ph + sW2C[b][11];
        float u0 = sK[b][0]*cx + sK[b][1]*cy + sK[b][2]*cz;
        float v0 = sK[b][3]*cx + sK[b][4]*cy + sK[b][5]*cz;
        float zc = sK[b][6]*cx + sK[b][7]*cy + sK[b][8]*cz;
        float zsafe = (fabsf(zc) < 1e-6f) ? 1e-6f : zc;
        float u = u0 / zsafe;
        float v = v0 / zsafe;
        bool mask = (zc > 1e-3f) && (u >= 0.0f) && (u < (float)IMG_W)
                                 && (v >= 0.0f) && (v < (float)IMG_H);
        if (!mask) continue;

        wsum += 1.0f;
        zsum += zc;
        {
            float xf = v * 0.25f - 0.5f;
            float yf = u * 0.25f - 0.5f;
            float x0f = floorf(xf), y0f = floorf(yf);
            float wx = xf - x0f, wy = yf - y0f;
            int x0 = (int)x0f, y0 = (int)y0f;
            float vx0 = (x0   >= 0 && x0   < FXV) ? 1.0f : 0.0f;
            float vx1 = (x0+1 >= 0 && x0+1 < FXV) ? 1.0f : 0.0f;
            float vy0 = (y0   >= 0 && y0   < FZV) ? 1.0f : 0.0f;
            float vy1 = (y0+1 >= 0 && y0+1 < FZV) ? 1.0f : 0.0f;
            float w00 = (1.0f-wx)*(1.0f-wy)*vx0*vy0;
            float w10 = wx*(1.0f-wy)*vx1*vy0;
            float w01 = (1.0f-wx)*wy*vx0*vy1;
            float w11 = wx*wy*vx1*vy1;
            int xi0 = min(max(x0,   0), FXV-1), xi1 = min(max(x0+1, 0), FXV-1);
            int yi0 = min(max(y0,   0), FZV-1), yi1 = min(max(y0+1, 0), FZV-1);
            int o00 = xi0*FZV + yi0, o01 = xi0*FZV + yi1;
            int o10 = xi1*FZV + yi0, o11 = xi1*FZV + yi1;
            const float* p = img_feats + (size_t)b * (CCH*FXV*FZV);
            #pragma unroll
            for (int c = 0; c < CCH; c++) {
                const float* pc = p + c * (FXV*FZV);
                fsum[c] += w00*pc[o00] + w01*pc[o01] + w10*pc[o10] + w11*pc[o11];
            }
        }
        {
            float xf = v - 0.5f;
            float yf = u - 0.5f;
            float x0f = floorf(xf), y0f = floorf(yf);
            float wx = xf - x0f, wy = yf - y0f;
            int x0 = (int)x0f, y0 = (int)y0f;
            float vx0 = (x0   >= 0 && x0   < IMG_H) ? 1.0f : 0.0f;
            float vx1 = (x0+1 >= 0 && x0+1 < IMG_H) ? 1.0f : 0.0f;
            float vy0 = (y0   >= 0 && y0   < IMG_W) ? 1.0f : 0.0f;
            float vy1 = (y0+1 >= 0 && y0+1 < IMG_W) ? 1.0f : 0.0f;
            float w00 = (1.0f-wx)*(1.0f-wy)*vx0*vy0;
            float w10 = wx*(1.0f-wy)*vx1*vy0;
            float w01 = (1.0f-wx)*wy*vx0*vy1;
            float w11 = wx*wy*vx1*vy1;
            int xi0 = min(max(x0,   0), IMG_H-1), xi1 = min(max(x0+1, 0), IMG_H-1);
            int yi0 = min(max(y0,   0), IMG_W-1), yi1 = min(max(y0+1, 0), IMG_W-1);
            int o00 = xi0*IMG_W + yi0, o01 = xi0*IMG_W + yi1;
            int o10 = xi1*IMG_W + yi0, o11 = xi1*IMG_W + yi1;
            const float* pv = variances    + (size_t)b * (IMG_H*IMG_W);
            const float* pd = render_depth + (size_t)b * (IMG_H*IMG_W);
            vsum  += w00*pv[o00] + w01*pv[o01] + w10*pv[o10] + w11*pv[o11];
            ndsum += w00*pd[o00] + w01*pd[o01] + w10*pd[o10] + w11*pd[o11];
        }
    }

    float invd = 1.0f / (wsum + 1e-6f);
    #pragma unroll
    for (int c = 0; c < CCH; c++) out[(size_t)c * NVOX + n] = fsum[c] * invd;
    out[(size_t)CCH*NVOX + n]              = vsum  * invd;
    out[(size_t)CCH*NVOX + NVOX + n]       = zsum  * invd;
    out[(size_t)CCH*NVOX + 2*(size_t)NVOX + n] = ndsum * invd;
}

extern "C" void kernel_launch(void* const* d_in, const int* in_sizes, int n_in,
                              void* d_out, int out_size, void* d_ws, size_t ws_size,
                              hipStream_t stream) {
    const float* img_feats    = (const float*)d_in[0];
    const float* variances    = (const float*)d_in[1];
    const float* render_depth = (const float*)d_in[2];
    const float* coords       = (const float*)d_in[3];
    const float* Ps           = (const float*)d_in[4];
    const float* Ks           = (const float*)d_in[5];
    float* out = (float*)d_out;

    if (ws_size >= WS_NEED_BYTES) {
        float* feats_t = (float*)d_ws;
        float* vd_t    = feats_t + FEATS_T_ELEMS;
        {
            int total = NF + NV;
            hipLaunchKernelGGL(prep_all, dim3((total + 255) / 256), dim3(256), 0, stream,
                               img_feats, variances, render_depth, feats_t, vd_t);
        }
        hipLaunchKernelGGL(mvmap_fast, dim3(NVOX / 256), dim3(256), 0, stream,
                           feats_t, vd_t, coords, Ps, Ks, out);
    } else {
        hipLaunchKernelGGL(mvmap_main, dim3(NVOX / 256), dim3(256), 0, stream,
                           img_feats, variances, render_depth, coords, Ps, Ks, out);
    }
}

// Round 9
// 47.650 us; speedup vs baseline: 1.0656x; 1.0656x over previous
//
#include <hip/hip_runtime.h>
#include <math.h>

#define NCAMS 6
#define CCH   32
#define YY    8
#define XX    256
#define ZZ    256
#define NVOX  (YY*XX*ZZ)        // 524288
#define IMG_H 224
#define IMG_W 400
#define FXV   56
#define FZV   100

#define NF (NCAMS*FXV*FZV)          // 33600 feat pixels
#define NV (NCAMS*IMG_H*IMG_W)      // 537600 vd pixels
#define FEATS_T_ELEMS (NF*CCH)      // 1,075,200
#define VD_T_ELEMS    (NV*2)        // 1,075,200
#define WS_NEED_BYTES ((size_t)(FEATS_T_ELEMS + VD_T_ELEMS) * 4)

// ---------------- fused prep: feats [6,32,56,100]->[6,56,100,32]; var+dep -> [6,224,400,2]
__global__ __launch_bounds__(256) void prep_all(
    const float* __restrict__ src_f, const float* __restrict__ var,
    const float* __restrict__ dep, float* __restrict__ dst_f,
    float* __restrict__ dst_vd)
{
    int t = blockIdx.x * 256 + threadIdx.x;
    if (t < NF) {
        int b = t / (FXV * FZV);
        int r = t - b * (FXV * FZV);
        float4* d4 = (float4*)(dst_f + (size_t)t * CCH);
        #pragma unroll
        for (int j = 0; j < CCH / 4; j++) {
            float4 v;
            v.x = src_f[(size_t)(b * CCH + 4*j + 0) * (FXV*FZV) + r];
            v.y = src_f[(size_t)(b * CCH + 4*j + 1) * (FXV*FZV) + r];
            v.z = src_f[(size_t)(b * CCH + 4*j + 2) * (FXV*FZV) + r];
            v.w = src_f[(size_t)(b * CCH + 4*j + 3) * (FXV*FZV) + r];
            d4[j] = v;
        }
    } else {
        int u = t - NF;
        if (u < NV) ((float2*)dst_vd)[u] = make_float2(var[u], dep[u]);
    }
}

// ---- main: 256-thread blocks = 4 independent waves, wave = 64 voxels.
//      Phase1 lane=voxel (project+vd+aux). Phase2: two passes of 4 sub-rounds
//      (8 lanes/voxel x 4 channels, unique-line gathers) -> per-wave 32x33 LDS
//      transpose -> 128B-contiguous full-line channel stores (round-7 quality)
//      at 32 waves/CU occupancy.
__global__ __launch_bounds__(256, 8) void mvmap_fast(
    const float* __restrict__ feats_t,   // [6,56,100,32]
    const float* __restrict__ vd_t,      // [6,224,400,2]
    const float* __restrict__ coords,    // [1,524288,3]  (px, pz, h)
    const float* __restrict__ Ps,        // [6,4,4] cam2world
    const float* __restrict__ Ks,        // [6,3,3]
    float* __restrict__ out)
{
    __shared__ float4 sW2C[NCAMS][3];   // rows [i0 i1 i2 | t]
    __shared__ float4 sK[NCAMS][3];     // rows of K (w unused)
    __shared__ float  sT[4][32 * 33];   // per-wave half-tile transpose buffer

    if (threadIdx.x < NCAMS) {
        int b = threadIdx.x;
        const float* P = Ps + b * 16;
        float r00=P[0], r01=P[1], r02=P[2],  tx=P[3];
        float r10=P[4], r11=P[5], r12=P[6],  ty=P[7];
        float r20=P[8], r21=P[9], r22=P[10], tz=P[11];
        float det = r00*(r11*r22 - r12*r21)
                  - r01*(r10*r22 - r12*r20)
                  + r02*(r10*r21 - r11*r20);
        float id = 1.0f / det;
        float i00 =  (r11*r22 - r12*r21) * id;
        float i01 = -(r01*r22 - r02*r21) * id;
        float i02 =  (r01*r12 - r02*r11) * id;
        float i10 = -(r10*r22 - r12*r20) * id;
        float i11 =  (r00*r22 - r02*r20) * id;
        float i12 = -(r00*r12 - r02*r10) * id;
        float i20 =  (r10*r21 - r11*r20) * id;
        float i21 = -(r00*r21 - r01*r20) * id;
        float i22 =  (r00*r11 - r01*r10) * id;
        sW2C[b][0] = make_float4(i00, i01, i02, -(i00*tx + i01*ty + i02*tz));
        sW2C[b][1] = make_float4(i10, i11, i12, -(i10*tx + i11*ty + i12*tz));
        sW2C[b][2] = make_float4(i20, i21, i22, -(i20*tx + i21*ty + i22*tz));
        sK[b][0] = make_float4(Ks[b*9+0], Ks[b*9+1], Ks[b*9+2], 0.f);
        sK[b][1] = make_float4(Ks[b*9+3], Ks[b*9+4], Ks[b*9+5], 0.f);
        sK[b][2] = make_float4(Ks[b*9+6], Ks[b*9+7], Ks[b*9+8], 0.f);
    }
    __syncthreads();

    int wv   = threadIdx.x >> 6;             // wave within block (0..3)
    int lane = threadIdx.x & 63;             // lane within wave
    int n0   = blockIdx.x * 256 + wv * 64;   // wave's 64-voxel base
    int n    = n0 + lane;                    // this lane's voxel

    float px = coords[3*n + 0];
    float pz = coords[3*n + 1];
    float ph = coords[3*n + 2];

    // ---------------- phase 1: projection + mask, compact into slots (lane = voxel)
    float wsum = 0.0f, zsum = 0.0f;
    int   nvis = 0;
    float s_u[3] = {0.f, 0.f, 0.f};
    float s_v[3] = {0.f, 0.f, 0.f};
    int   s_b[3] = {0, 0, 0};

    #pragma unroll
    for (int b = 0; b < NCAMS; b++) {
        float4 r0 = sW2C[b][0], r1 = sW2C[b][1], r2 = sW2C[b][2];
        float cx = r0.x*px + r0.y*pz + r0.z*ph + r0.w;
        float cy = r1.x*px + r1.y*pz + r1.z*ph + r1.w;
        float cz = r2.x*px + r2.y*pz + r2.z*ph + r2.w;
        float4 k0 = sK[b][0], k1 = sK[b][1], k2 = sK[b][2];
        float u0 = k0.x*cx + k0.y*cy + k0.z*cz;
        float v0 = k1.x*cx + k1.y*cy + k1.z*cz;
        float zc = k2.x*cx + k2.y*cy + k2.z*cz;
        float zsafe = (fabsf(zc) < 1e-6f) ? 1e-6f : zc;
        float u = u0 / zsafe;                 // exact IEEE divide (mask bit-identity)
        float v = v0 / zsafe;
        bool mask = (zc > 1e-3f) && (u >= 0.0f) && (u < (float)IMG_W)
                                 && (v >= 0.0f) && (v < (float)IMG_H);
        wsum += mask ? 1.0f : 0.0f;
        zsum += mask ? zc : 0.0f;
        bool c0 = mask && (nvis == 0);
        bool c1 = mask && (nvis == 1);
        bool c2 = mask && (nvis == 2);        // geometrically dead (HFOV 77 < 120), defensive
        s_u[0] = c0 ? u : s_u[0];  s_v[0] = c0 ? v : s_v[0];  s_b[0] = c0 ? b : s_b[0];
        s_u[1] = c1 ? u : s_u[1];  s_v[1] = c1 ? v : s_v[1];  s_b[1] = c1 ? b : s_b[1];
        s_u[2] = c2 ? u : s_u[2];  s_v[2] = c2 ? v : s_v[2];  s_b[2] = c2 ? b : s_b[2];
        nvis += mask ? 1 : 0;
    }
    float invd = 1.0f / (wsum + 1e-6f);

    // ---------------- phase 1b: variance + depth bilinear (lane = voxel)
    float vsum = 0.0f, ndsum = 0.0f;
    #pragma unroll
    for (int it = 0; it < 3; it++) {
        if (it < nvis) {
            float u = s_u[it], v = s_v[it];
            int   b = s_b[it];
            float xf = v - 0.5f;
            float yf = u - 0.5f;
            float x0f = floorf(xf), y0f = floorf(yf);
            float wx = xf - x0f, wy = yf - y0f;
            int x0 = (int)x0f, y0 = (int)y0f;
            float vx0 = (x0   >= 0 && x0   < IMG_H) ? 1.0f : 0.0f;
            float vx1 = (x0+1 >= 0 && x0+1 < IMG_H) ? 1.0f : 0.0f;
            float vy0 = (y0   >= 0 && y0   < IMG_W) ? 1.0f : 0.0f;
            float vy1 = (y0+1 >= 0 && y0+1 < IMG_W) ? 1.0f : 0.0f;
            float w00 = (1.0f-wx)*(1.0f-wy)*vx0*vy0;
            float w10 = wx*(1.0f-wy)*vx1*vy0;
            float w01 = (1.0f-wx)*wy*vx0*vy1;
            float w11 = wx*wy*vx1*vy1;
            int xi0 = min(max(x0,   0), IMG_H-1), xi1 = min(max(x0+1, 0), IMG_H-1);
            int yi0 = min(max(y0,   0), IMG_W-1), yi1 = min(max(y0+1, 0), IMG_W-1);
            const float2* pv = (const float2*)(vd_t) + (size_t)b * (IMG_H*IMG_W);
            float2 t00 = pv[xi0*IMG_W + yi0], t01 = pv[xi0*IMG_W + yi1];
            float2 t10 = pv[xi1*IMG_W + yi0], t11 = pv[xi1*IMG_W + yi1];
            vsum  += w00*t00.x + w01*t01.x + w10*t10.x + w11*t11.x;
            ndsum += w00*t00.y + w01*t01.y + w10*t10.y + w11*t11.y;
        }
    }
    __builtin_nontemporal_store(vsum  * invd, &out[(size_t)CCH*NVOX + n]);
    __builtin_nontemporal_store(zsum  * invd, &out[(size_t)CCH*NVOX + NVOX + n]);
    __builtin_nontemporal_store(ndsum * invd, &out[(size_t)CCH*NVOX + 2*(size_t)NVOX + n]);

    // ---------------- phase 2: two passes x 4 sub-rounds; 8 lanes/voxel x 4 channels
    int cg = lane & 7;        // channel group: channels 4*cg .. 4*cg+3
    int vg = lane >> 3;       // voxel offset within each 8-voxel sub-round

    #pragma unroll
    for (int p = 0; p < 2; p++) {
        #pragma unroll
        for (int sr = 0; sr < 4; sr++) {
            int s   = 4*p + sr;
            int src = 8*s + vg;                 // lane owning this voxel's projection

            // ---- HOISTED broadcasts: executed by ALL lanes (defined behavior) ----
            int   nv  = __shfl(nvis, src);
            float iv  = __shfl(invd, src);
            float uu0 = __shfl(s_u[0], src), vv0 = __shfl(s_v[0], src);
            float uu1 = __shfl(s_u[1], src), vv1 = __shfl(s_v[1], src);
            float uu2 = __shfl(s_u[2], src), vv2 = __shfl(s_v[2], src);
            int   bb0 = __shfl(s_b[0], src);
            int   bb1 = __shfl(s_b[1], src);
            int   bb2 = __shfl(s_b[2], src);
            float uu[3] = {uu0, uu1, uu2};
            float vv[3] = {vv0, vv1, vv2};
            int   bb[3] = {bb0, bb1, bb2};

            float ax = 0.f, ay = 0.f, az = 0.f, aw = 0.f;
            #pragma unroll
            for (int it = 0; it < 3; it++) {
                if (it < nv) {
                    float u = uu[it], v = vv[it];
                    int   b = bb[it];
                    float xf = v * 0.25f - 0.5f;      // width dim (56)
                    float yf = u * 0.25f - 0.5f;      // height dim (100)
                    float x0f = floorf(xf), y0f = floorf(yf);
                    float wx = xf - x0f, wy = yf - y0f;
                    int x0 = (int)x0f, y0 = (int)y0f;
                    float vx0 = (x0   >= 0 && x0   < FXV) ? 1.0f : 0.0f;
                    float vx1 = (x0+1 >= 0 && x0+1 < FXV) ? 1.0f : 0.0f;
                    float vy0 = (y0   >= 0 && y0   < FZV) ? 1.0f : 0.0f;
                    float vy1 = (y0+1 >= 0 && y0+1 < FZV) ? 1.0f : 0.0f;
                    float w00 = (1.0f-wx)*(1.0f-wy)*vx0*vy0;
                    float w10 = wx*(1.0f-wy)*vx1*vy0;
                    float w01 = (1.0f-wx)*wy*vx0*vy1;
                    float w11 = wx*wy*vx1*vy1;
                    int xi0 = min(max(x0,   0), FXV-1), xi1 = min(max(x0+1, 0), FXV-1);
                    int yi0 = min(max(y0,   0), FZV-1), yi1 = min(max(y0+1, 0), FZV-1);
                    const float* base = feats_t + (size_t)b * (FXV*FZV*CCH) + cg * 4;
                    float4 a  = *(const float4*)(base + (size_t)(xi0*FZV + yi0)*CCH);
                    float4 b2 = *(const float4*)(base + (size_t)(xi0*FZV + yi1)*CCH);
                    float4 c2 = *(const float4*)(base + (size_t)(xi1*FZV + yi0)*CCH);
                    float4 d2 = *(const float4*)(base + (size_t)(xi1*FZV + yi1)*CCH);
                    ax += w00*a.x + w01*b2.x + w10*c2.x + w11*d2.x;
                    ay += w00*a.y + w01*b2.y + w10*c2.y + w11*d2.y;
                    az += w00*a.z + w01*b2.z + w10*c2.z + w11*d2.z;
                    aw += w00*a.w + w01*b2.w + w10*c2.w + w11*d2.w;
                }
            }
            // local voxel row within this pass's 32-voxel half-tile
            float* pt = &sT[wv][(8*sr + vg) * 33 + cg * 4];
            pt[0] = ax * iv;
            pt[1] = ay * iv;
            pt[2] = az * iv;
            pt[3] = aw * iv;
        }
        __syncthreads();

        // ---- transpose-store: 16 instrs, each 2 channels x 32 voxels (2x128B lines)
        int row  = lane & 31;                    // voxel within half-tile
        int half = lane >> 5;                    // 0: even channel, 1: odd channel
        int vn   = n0 + 32*p + row;
        #pragma unroll
        for (int i = 0; i < 16; i++) {
            int c = 2*i + half;
            float val = sT[wv][row * 33 + c];
            __builtin_nontemporal_store(val, &out[(size_t)c * NVOX + vn]);
        }
        __syncthreads();
    }
}

// ---------------- fallback (original layouts, one thread per voxel) --------------
__global__ __launch_bounds__(256) void mvmap_main(
    const float* __restrict__ img_feats,
    const float* __restrict__ variances,
    const float* __restrict__ render_depth,
    const float* __restrict__ coords,
    const float* __restrict__ Ps,
    const float* __restrict__ Ks,
    float* __restrict__ out)
{
    __shared__ float sW2C[NCAMS][12];
    __shared__ float sK[NCAMS][9];

    if (threadIdx.x < NCAMS) {
        int b = threadIdx.x;
        const float* P = Ps + b * 16;
        float r00=P[0], r01=P[1], r02=P[2],  tx=P[3];
        float r10=P[4], r11=P[5], r12=P[6],  ty=P[7];
        float r20=P[8], r21=P[9], r22=P[10], tz=P[11];
        float det = r00*(r11*r22 - r12*r21)
                  - r01*(r10*r22 - r12*r20)
                  + r02*(r10*r21 - r11*r20);
        float id = 1.0f / det;
        float i00 =  (r11*r22 - r12*r21) * id;
        float i01 = -(r01*r22 - r02*r21) * id;
        float i02 =  (r01*r12 - r02*r11) * id;
        float i10 = -(r10*r22 - r12*r20) * id;
        float i11 =  (r00*r22 - r02*r20) * id;
        float i12 = -(r00*r12 - r02*r10) * id;
        float i20 =  (r10*r21 - r11*r20) * id;
        float i21 = -(r00*r21 - r01*r20) * id;
        float i22 =  (r00*r11 - r01*r10) * id;
        sW2C[b][0]=i00; sW2C[b][1]=i01; sW2C[b][2] =i02; sW2C[b][3] =-(i00*tx + i01*ty + i02*tz);
        sW2C[b][4]=i10; sW2C[b][5]=i11; sW2C[b][6] =i12; sW2C[b][7] =-(i10*tx + i11*ty + i12*tz);
        sW2C[b][8]=i20; sW2C[b][9]=i21; sW2C[b][10]=i22; sW2C[b][11]=-(i20*tx + i21*ty + i22*tz);
        #pragma unroll
        for (int jj = 0; jj < 9; jj++) sK[b][jj] = Ks[b*9 + jj];
    }
    __syncthreads();

    int n = blockIdx.x * blockDim.x + threadIdx.x;
    if (n >= NVOX) return;

    float px = coords[3*n + 0];
    float pz = coords[3*n + 1];
    float ph = coords[3*n + 2];

    float fsum[CCH];
    #pragma unroll
    for (int c = 0; c < CCH; c++) fsum[c] = 0.0f;
    float wsum = 0.0f, vsum = 0.0f, ndsum = 0.0f, zsum = 0.0f;

    for (int b = 0; b < NCAMS; b++) {
        float cx = sW2C[b][0]*px + sW2C[b][1]*pz + sW2C[b][2] *ph + sW2C[b][3];
        float cy = sW2C[b][4]*px + sW2C[b][5]*pz + sW2C[b][6] *ph + sW2C[b][7];
        float cz = sW2C[b][8]*px + sW2C[b][9]*pz + sW2C[b][10]*ph + sW2C[b][11];
        float u0 = sK[b][0]*cx + sK[b][1]*cy + sK[b][2]*cz;
        float v0 = sK[b][3]*cx + sK[b][4]*cy + sK[b][5]*cz;
        float zc = sK[b][6]*cx + sK[b][7]*cy + sK[b][8]*cz;
        float zsafe = (fabsf(zc) < 1e-6f) ? 1e-6f : zc;
        float u = u0 / zsafe;
        float v = v0 / zsafe;
        bool mask = (zc > 1e-3f) && (u >= 0.0f) && (u < (float)IMG_W)
                                 && (v >= 0.0f) && (v < (float)IMG_H);
        if (!mask) continue;

        wsum += 1.0f;
        zsum += zc;
        {
            float xf = v * 0.25f - 0.5f;
            float yf = u * 0.25f - 0.5f;
            float x0f = floorf(xf), y0f = floorf(yf);
            float wx = xf - x0f, wy = yf - y0f;
            int x0 = (int)x0f, y0 = (int)y0f;
            float vx0 = (x0   >= 0 && x0   < FXV) ? 1.0f : 0.0f;
            float vx1 = (x0+1 >= 0 && x0+1 < FXV) ? 1.0f : 0.0f;
            float vy0 = (y0   >= 0 && y0   < FZV) ? 1.0f : 0.0f;
            float vy1 = (y0+1 >= 0 && y0+1 < FZV) ? 1.0f : 0.0f;
            float w00 = (1.0f-wx)*(1.0f-wy)*vx0*vy0;
            float w10 = wx*(1.0f-wy)*vx1*vy0;
            float w01 = (1.0f-wx)*wy*vx0*vy1;
            float w11 = wx*wy*vx1*vy1;
            int xi0 = min(max(x0,   0), FXV-1), xi1 = min(max(x0+1, 0), FXV-1);
            int yi0 = min(max(y0,   0), FZV-1), yi1 = min(max(y0+1, 0), FZV-1);
            int o00 = xi0*FZV + yi0, o01 = xi0*FZV + yi1;
            int o10 = xi1*FZV + yi0, o11 = xi1*FZV + yi1;
            const float* p = img_feats + (size_t)b * (CCH*FXV*FZV);
            #pragma unroll
            for (int c = 0; c < CCH; c++) {
                const float* pc = p + c * (FXV*FZV);
                fsum[c] += w00*pc[o00] + w01*pc[o01] + w10*pc[o10] + w11*pc[o11];
            }
        }
        {
            float xf = v - 0.5f;
            float yf = u - 0.5f;
            float x0f = floorf(xf), y0f = floorf(yf);
            float wx = xf - x0f, wy = yf - y0f;
            int x0 = (int)x0f, y0 = (int)y0f;
            float vx0 = (x0   >= 0 && x0   < IMG_H) ? 1.0f : 0.0f;
            float vx1 = (x0+1 >= 0 && x0+1 < IMG_H) ? 1.0f : 0.0f;
            float vy0 = (y0   >= 0 && y0   < IMG_W) ? 1.0f : 0.0f;
            float vy1 = (y0+1 >= 0 && y0+1 < IMG_W) ? 1.0f : 0.0f;
            float w00 = (1.0f-wx)*(1.0f-wy)*vx0*vy0;
            float w10 = wx*(1.0f-wy)*vx1*vy0;
            float w01 = (1.0f-wx)*wy*vx0*vy1;
            float w11 = wx*wy*vx1*vy1;
            int xi0 = min(max(x0,   0), IMG_H-1), xi1 = min(max(x0+1, 0), IMG_H-1);
            int yi0 = min(max(y0,   0), IMG_W-1), yi1 = min(max(y0+1, 0), IMG_W-1);
            int o00 = xi0*IMG_W + yi0, o01 = xi0*IMG_W + yi1;
            int o10 = xi1*IMG_W + yi0, o11 = xi1*IMG_W + yi1;
            const float* pv = variances    + (size_t)b * (IMG_H*IMG_W);
            const float* pd = render_depth + (size_t)b * (IMG_H*IMG_W);
            vsum  += w00*pv[o00] + w01*pv[o01] + w10*pv[o10] + w11*pv[o11];
            ndsum += w00*pd[o00] + w01*pd[o01] + w10*pd[o10] + w11*pd[o11];
        }
    }

    float invd = 1.0f / (wsum + 1e-6f);
    #pragma unroll
    for (int c = 0; c < CCH; c++) out[(size_t)c * NVOX + n] = fsum[c] * invd;
    out[(size_t)CCH*NVOX + n]              = vsum  * invd;
    out[(size_t)CCH*NVOX + NVOX + n]       = zsum  * invd;
    out[(size_t)CCH*NVOX + 2*(size_t)NVOX + n] = ndsum * invd;
}

extern "C" void kernel_launch(void* const* d_in, const int* in_sizes, int n_in,
                              void* d_out, int out_size, void* d_ws, size_t ws_size,
                              hipStream_t stream) {
    const float* img_feats    = (const float*)d_in[0];
    const float* variances    = (const float*)d_in[1];
    const float* render_depth = (const float*)d_in[2];
    const float* coords       = (const float*)d_in[3];
    const float* Ps           = (const float*)d_in[4];
    const float* Ks           = (const float*)d_in[5];
    float* out = (float*)d_out;

    if (ws_size >= WS_NEED_BYTES) {
        float* feats_t = (float*)d_ws;
        float* vd_t    = feats_t + FEATS_T_ELEMS;
        {
            int total = NF + NV;
            hipLaunchKernelGGL(prep_all, dim3((total + 255) / 256), dim3(256), 0, stream,
                               img_feats, variances, render_depth, feats_t, vd_t);
        }
        hipLaunchKernelGGL(mvmap_fast, dim3(NVOX / 256), dim3(256), 0, stream,
                           feats_t, vd_t, coords, Ps, Ks, out);
    } else {
        hipLaunchKernelGGL(mvmap_main, dim3(NVOX / 256), dim3(256), 0, stream,
                           img_feats, variances, render_depth, coords, Ps, Ks, out);
    }
}

// Round 10
// 42.253 us; speedup vs baseline: 1.2018x; 1.1277x over previous
//
#include <hip/hip_runtime.h>
#include <math.h>

#define NCAMS 6
#define CCH   32
#define YY    8
#define XX    256
#define ZZ    256
#define NVOX  (YY*XX*ZZ)        // 524288
#define IMG_H 224
#define IMG_W 400
#define FXV   56
#define FZV   100

#define NF (NCAMS*FXV*FZV)          // 33600 feat pixels
#define NV (NCAMS*IMG_H*IMG_W)      // 537600 vd pixels
#define FEATS_T_ELEMS (NF*CCH)      // 1,075,200
#define VD_T_ELEMS    (NV*2)        // 1,075,200
#define WS_NEED_BYTES ((size_t)(FEATS_T_ELEMS + VD_T_ELEMS) * 4)

// ---------------- fused prep: feats [6,32,56,100]->[6,56,100,32]; var+dep -> [6,224,400,2]
__global__ __launch_bounds__(256) void prep_all(
    const float* __restrict__ src_f, const float* __restrict__ var,
    const float* __restrict__ dep, float* __restrict__ dst_f,
    float* __restrict__ dst_vd)
{
    int t = blockIdx.x * 256 + threadIdx.x;
    if (t < NF) {
        int b = t / (FXV * FZV);
        int r = t - b * (FXV * FZV);
        float4* d4 = (float4*)(dst_f + (size_t)t * CCH);
        #pragma unroll
        for (int j = 0; j < CCH / 4; j++) {
            float4 v;
            v.x = src_f[(size_t)(b * CCH + 4*j + 0) * (FXV*FZV) + r];
            v.y = src_f[(size_t)(b * CCH + 4*j + 1) * (FXV*FZV) + r];
            v.z = src_f[(size_t)(b * CCH + 4*j + 2) * (FXV*FZV) + r];
            v.w = src_f[(size_t)(b * CCH + 4*j + 3) * (FXV*FZV) + r];
            d4[j] = v;
        }
    } else {
        int u = t - NF;
        if (u < NV) ((float2*)dst_vd)[u] = make_float2(var[u], dep[u]);
    }
}

// ---- main: 256-thread blocks = 4 independent waves, wave = 64 voxels.
//      Phase1 lane=voxel (project+vd+aux). Phase2: two passes of 4 sub-rounds
//      (8 lanes/voxel x 4 channels, unique-line gathers) -> per-wave 32x33 LDS
//      transpose -> 128B-contiguous full-line channel stores.
//      launch_bounds(256,4): VGPR cap 128 (round 9's (256,8) cap=64 -> actual 32
//      -> spilled ~64B/voxel to scratch, +33MB WRITE. Never cap below liveness.)
__global__ __launch_bounds__(256, 4) void mvmap_fast(
    const float* __restrict__ feats_t,   // [6,56,100,32]
    const float* __restrict__ vd_t,      // [6,224,400,2]
    const float* __restrict__ coords,    // [1,524288,3]  (px, pz, h)
    const float* __restrict__ Ps,        // [6,4,4] cam2world
    const float* __restrict__ Ks,        // [6,3,3]
    float* __restrict__ out)
{
    __shared__ float4 sW2C[NCAMS][3];   // rows [i0 i1 i2 | t]
    __shared__ float4 sK[NCAMS][3];     // rows of K (w unused)
    __shared__ float  sT[4][32 * 33];   // per-wave half-tile transpose buffer

    if (threadIdx.x < NCAMS) {
        int b = threadIdx.x;
        const float* P = Ps + b * 16;
        float r00=P[0], r01=P[1], r02=P[2],  tx=P[3];
        float r10=P[4], r11=P[5], r12=P[6],  ty=P[7];
        float r20=P[8], r21=P[9], r22=P[10], tz=P[11];
        float det = r00*(r11*r22 - r12*r21)
                  - r01*(r10*r22 - r12*r20)
                  + r02*(r10*r21 - r11*r20);
        float id = 1.0f / det;
        float i00 =  (r11*r22 - r12*r21) * id;
        float i01 = -(r01*r22 - r02*r21) * id;
        float i02 =  (r01*r12 - r02*r11) * id;
        float i10 = -(r10*r22 - r12*r20) * id;
        float i11 =  (r00*r22 - r02*r20) * id;
        float i12 = -(r00*r12 - r02*r10) * id;
        float i20 =  (r10*r21 - r11*r20) * id;
        float i21 = -(r00*r21 - r01*r20) * id;
        float i22 =  (r00*r11 - r01*r10) * id;
        sW2C[b][0] = make_float4(i00, i01, i02, -(i00*tx + i01*ty + i02*tz));
        sW2C[b][1] = make_float4(i10, i11, i12, -(i10*tx + i11*ty + i12*tz));
        sW2C[b][2] = make_float4(i20, i21, i22, -(i20*tx + i21*ty + i22*tz));
        sK[b][0] = make_float4(Ks[b*9+0], Ks[b*9+1], Ks[b*9+2], 0.f);
        sK[b][1] = make_float4(Ks[b*9+3], Ks[b*9+4], Ks[b*9+5], 0.f);
        sK[b][2] = make_float4(Ks[b*9+6], Ks[b*9+7], Ks[b*9+8], 0.f);
    }
    __syncthreads();

    int wv   = threadIdx.x >> 6;             // wave within block (0..3)
    int lane = threadIdx.x & 63;             // lane within wave
    int n0   = blockIdx.x * 256 + wv * 64;   // wave's 64-voxel base
    int n    = n0 + lane;                    // this lane's voxel

    float px = coords[3*n + 0];
    float pz = coords[3*n + 1];
    float ph = coords[3*n + 2];

    // ---------------- phase 1: projection + mask, compact into slots (lane = voxel)
    float wsum = 0.0f, zsum = 0.0f;
    int   nvis = 0;
    float s_u[3] = {0.f, 0.f, 0.f};
    float s_v[3] = {0.f, 0.f, 0.f};
    int   s_b[3] = {0, 0, 0};

    #pragma unroll
    for (int b = 0; b < NCAMS; b++) {
        float4 r0 = sW2C[b][0], r1 = sW2C[b][1], r2 = sW2C[b][2];
        float cx = r0.x*px + r0.y*pz + r0.z*ph + r0.w;
        float cy = r1.x*px + r1.y*pz + r1.z*ph + r1.w;
        float cz = r2.x*px + r2.y*pz + r2.z*ph + r2.w;
        float4 k0 = sK[b][0], k1 = sK[b][1], k2 = sK[b][2];
        float u0 = k0.x*cx + k0.y*cy + k0.z*cz;
        float v0 = k1.x*cx + k1.y*cy + k1.z*cz;
        float zc = k2.x*cx + k2.y*cy + k2.z*cz;
        float zsafe = (fabsf(zc) < 1e-6f) ? 1e-6f : zc;
        float u = u0 / zsafe;                 // exact IEEE divide (mask bit-identity)
        float v = v0 / zsafe;
        bool mask = (zc > 1e-3f) && (u >= 0.0f) && (u < (float)IMG_W)
                                 && (v >= 0.0f) && (v < (float)IMG_H);
        wsum += mask ? 1.0f : 0.0f;
        zsum += mask ? zc : 0.0f;
        bool c0 = mask && (nvis == 0);
        bool c1 = mask && (nvis == 1);
        bool c2 = mask && (nvis == 2);        // geometrically dead (HFOV 77 < 120), defensive
        s_u[0] = c0 ? u : s_u[0];  s_v[0] = c0 ? v : s_v[0];  s_b[0] = c0 ? b : s_b[0];
        s_u[1] = c1 ? u : s_u[1];  s_v[1] = c1 ? v : s_v[1];  s_b[1] = c1 ? b : s_b[1];
        s_u[2] = c2 ? u : s_u[2];  s_v[2] = c2 ? v : s_v[2];  s_b[2] = c2 ? b : s_b[2];
        nvis += mask ? 1 : 0;
    }
    float invd = 1.0f / (wsum + 1e-6f);

    // ---------------- phase 1b: variance + depth bilinear (lane = voxel)
    float vsum = 0.0f, ndsum = 0.0f;
    #pragma unroll
    for (int it = 0; it < 3; it++) {
        if (it < nvis) {
            float u = s_u[it], v = s_v[it];
            int   b = s_b[it];
            float xf = v - 0.5f;
            float yf = u - 0.5f;
            float x0f = floorf(xf), y0f = floorf(yf);
            float wx = xf - x0f, wy = yf - y0f;
            int x0 = (int)x0f, y0 = (int)y0f;
            float vx0 = (x0   >= 0 && x0   < IMG_H) ? 1.0f : 0.0f;
            float vx1 = (x0+1 >= 0 && x0+1 < IMG_H) ? 1.0f : 0.0f;
            float vy0 = (y0   >= 0 && y0   < IMG_W) ? 1.0f : 0.0f;
            float vy1 = (y0+1 >= 0 && y0+1 < IMG_W) ? 1.0f : 0.0f;
            float w00 = (1.0f-wx)*(1.0f-wy)*vx0*vy0;
            float w10 = wx*(1.0f-wy)*vx1*vy0;
            float w01 = (1.0f-wx)*wy*vx0*vy1;
            float w11 = wx*wy*vx1*vy1;
            int xi0 = min(max(x0,   0), IMG_H-1), xi1 = min(max(x0+1, 0), IMG_H-1);
            int yi0 = min(max(y0,   0), IMG_W-1), yi1 = min(max(y0+1, 0), IMG_W-1);
            const float2* pv = (const float2*)(vd_t) + (size_t)b * (IMG_H*IMG_W);
            float2 t00 = pv[xi0*IMG_W + yi0], t01 = pv[xi0*IMG_W + yi1];
            float2 t10 = pv[xi1*IMG_W + yi0], t11 = pv[xi1*IMG_W + yi1];
            vsum  += w00*t00.x + w01*t01.x + w10*t10.x + w11*t11.x;
            ndsum += w00*t00.y + w01*t01.y + w10*t10.y + w11*t11.y;
        }
    }
    __builtin_nontemporal_store(vsum  * invd, &out[(size_t)CCH*NVOX + n]);
    __builtin_nontemporal_store(zsum  * invd, &out[(size_t)CCH*NVOX + NVOX + n]);
    __builtin_nontemporal_store(ndsum * invd, &out[(size_t)CCH*NVOX + 2*(size_t)NVOX + n]);

    // ---------------- phase 2: two passes x 4 sub-rounds; 8 lanes/voxel x 4 channels
    int cg = lane & 7;        // channel group: channels 4*cg .. 4*cg+3
    int vg = lane >> 3;       // voxel offset within each 8-voxel sub-round

    #pragma unroll
    for (int p = 0; p < 2; p++) {
        #pragma unroll
        for (int sr = 0; sr < 4; sr++) {
            int s   = 4*p + sr;
            int src = 8*s + vg;                 // lane owning this voxel's projection

            // ---- HOISTED broadcasts: executed by ALL lanes (defined behavior) ----
            int   nv  = __shfl(nvis, src);
            float iv  = __shfl(invd, src);
            float uu0 = __shfl(s_u[0], src), vv0 = __shfl(s_v[0], src);
            float uu1 = __shfl(s_u[1], src), vv1 = __shfl(s_v[1], src);
            float uu2 = __shfl(s_u[2], src), vv2 = __shfl(s_v[2], src);
            int   bb0 = __shfl(s_b[0], src);
            int   bb1 = __shfl(s_b[1], src);
            int   bb2 = __shfl(s_b[2], src);
            float uu[3] = {uu0, uu1, uu2};
            float vv[3] = {vv0, vv1, vv2};
            int   bb[3] = {bb0, bb1, bb2};

            float ax = 0.f, ay = 0.f, az = 0.f, aw = 0.f;
            #pragma unroll
            for (int it = 0; it < 3; it++) {
                if (it < nv) {
                    float u = uu[it], v = vv[it];
                    int   b = bb[it];
                    float xf = v * 0.25f - 0.5f;      // width dim (56)
                    float yf = u * 0.25f - 0.5f;      // height dim (100)
                    float x0f = floorf(xf), y0f = floorf(yf);
                    float wx = xf - x0f, wy = yf - y0f;
                    int x0 = (int)x0f, y0 = (int)y0f;
                    float vx0 = (x0   >= 0 && x0   < FXV) ? 1.0f : 0.0f;
                    float vx1 = (x0+1 >= 0 && x0+1 < FXV) ? 1.0f : 0.0f;
                    float vy0 = (y0   >= 0 && y0   < FZV) ? 1.0f : 0.0f;
                    float vy1 = (y0+1 >= 0 && y0+1 < FZV) ? 1.0f : 0.0f;
                    float w00 = (1.0f-wx)*(1.0f-wy)*vx0*vy0;
                    float w10 = wx*(1.0f-wy)*vx1*vy0;
                    float w01 = (1.0f-wx)*wy*vx0*vy1;
                    float w11 = wx*wy*vx1*vy1;
                    int xi0 = min(max(x0,   0), FXV-1), xi1 = min(max(x0+1, 0), FXV-1);
                    int yi0 = min(max(y0,   0), FZV-1), yi1 = min(max(y0+1, 0), FZV-1);
                    const float* base = feats_t + (size_t)b * (FXV*FZV*CCH) + cg * 4;
                    float4 a  = *(const float4*)(base + (size_t)(xi0*FZV + yi0)*CCH);
                    float4 b2 = *(const float4*)(base + (size_t)(xi0*FZV + yi1)*CCH);
                    float4 c2 = *(const float4*)(base + (size_t)(xi1*FZV + yi0)*CCH);
                    float4 d2 = *(const float4*)(base + (size_t)(xi1*FZV + yi1)*CCH);
                    ax += w00*a.x + w01*b2.x + w10*c2.x + w11*d2.x;
                    ay += w00*a.y + w01*b2.y + w10*c2.y + w11*d2.y;
                    az += w00*a.z + w01*b2.z + w10*c2.z + w11*d2.z;
                    aw += w00*a.w + w01*b2.w + w10*c2.w + w11*d2.w;
                }
            }
            // local voxel row within this pass's 32-voxel half-tile
            float* pt = &sT[wv][(8*sr + vg) * 33 + cg * 4];
            pt[0] = ax * iv;
            pt[1] = ay * iv;
            pt[2] = az * iv;
            pt[3] = aw * iv;
        }
        __syncthreads();

        // ---- transpose-store: 16 instrs, each 2 channels x 32 voxels (2x128B lines)
        int row  = lane & 31;                    // voxel within half-tile
        int half = lane >> 5;                    // 0: even channel, 1: odd channel
        int vn   = n0 + 32*p + row;
        #pragma unroll
        for (int i = 0; i < 16; i++) {
            int c = 2*i + half;
            float val = sT[wv][row * 33 + c];
            __builtin_nontemporal_store(val, &out[(size_t)c * NVOX + vn]);
        }
        __syncthreads();
    }
}

// ---------------- fallback (original layouts, one thread per voxel) --------------
__global__ __launch_bounds__(256) void mvmap_main(
    const float* __restrict__ img_feats,
    const float* __restrict__ variances,
    const float* __restrict__ render_depth,
    const float* __restrict__ coords,
    const float* __restrict__ Ps,
    const float* __restrict__ Ks,
    float* __restrict__ out)
{
    __shared__ float sW2C[NCAMS][12];
    __shared__ float sK[NCAMS][9];

    if (threadIdx.x < NCAMS) {
        int b = threadIdx.x;
        const float* P = Ps + b * 16;
        float r00=P[0], r01=P[1], r02=P[2],  tx=P[3];
        float r10=P[4], r11=P[5], r12=P[6],  ty=P[7];
        float r20=P[8], r21=P[9], r22=P[10], tz=P[11];
        float det = r00*(r11*r22 - r12*r21)
                  - r01*(r10*r22 - r12*r20)
                  + r02*(r10*r21 - r11*r20);
        float id = 1.0f / det;
        float i00 =  (r11*r22 - r12*r21) * id;
        float i01 = -(r01*r22 - r02*r21) * id;
        float i02 =  (r01*r12 - r02*r11) * id;
        float i10 = -(r10*r22 - r12*r20) * id;
        float i11 =  (r00*r22 - r02*r20) * id;
        float i12 = -(r00*r12 - r02*r10) * id;
        float i20 =  (r10*r21 - r11*r20) * id;
        float i21 = -(r00*r21 - r01*r20) * id;
        float i22 =  (r00*r11 - r01*r10) * id;
        sW2C[b][0]=i00; sW2C[b][1]=i01; sW2C[b][2] =i02; sW2C[b][3] =-(i00*tx + i01*ty + i02*tz);
        sW2C[b][4]=i10; sW2C[b][5]=i11; sW2C[b][6] =i12; sW2C[b][7] =-(i10*tx + i11*ty + i12*tz);
        sW2C[b][8]=i20; sW2C[b][9]=i21; sW2C[b][10]=i22; sW2C[b][11]=-(i20*tx + i21*ty + i22*tz);
        #pragma unroll
        for (int jj = 0; jj < 9; jj++) sK[b][jj] = Ks[b*9 + jj];
    }
    __syncthreads();

    int n = blockIdx.x * blockDim.x + threadIdx.x;
    if (n >= NVOX) return;

    float px = coords[3*n + 0];
    float pz = coords[3*n + 1];
    float ph = coords[3*n + 2];

    float fsum[CCH];
    #pragma unroll
    for (int c = 0; c < CCH; c++) fsum[c] = 0.0f;
    float wsum = 0.0f, vsum = 0.0f, ndsum = 0.0f, zsum = 0.0f;

    for (int b = 0; b < NCAMS; b++) {
        float cx = sW2C[b][0]*px + sW2C[b][1]*pz + sW2C[b][2] *ph + sW2C[b][3];
        float cy = sW2C[b][4]*px + sW2C[b][5]*pz + sW2C[b][6] *ph + sW2C[b][7];
        float cz = sW2C[b][8]*px + sW2C[b][9]*pz + sW2C[b][10]*ph + sW2C[b][11];
        float u0 = sK[b][0]*cx + sK[b][1]*cy + sK[b][2]*cz;
        float v0 = sK[b][3]*cx + sK[b][4]*cy + sK[b][5]*cz;
        float zc = sK[b][6]*cx + sK[b][7]*cy + sK[b][8]*cz;
        float zsafe = (fabsf(zc) < 1e-6f) ? 1e-6f : zc;
        float u = u0 / zsafe;
        float v = v0 / zsafe;
        bool mask = (zc > 1e-3f) && (u >= 0.0f) && (u < (float)IMG_W)
                                 && (v >= 0.0f) && (v < (float)IMG_H);
        if (!mask) continue;

        wsum += 1.0f;
        zsum += zc;
        {
            float xf = v * 0.25f - 0.5f;
            float yf = u * 0.25f - 0.5f;
            float x0f = floorf(xf), y0f = floorf(yf);
            float wx = xf - x0f, wy = yf - y0f;
            int x0 = (int)x0f, y0 = (int)y0f;
            float vx0 = (x0   >= 0 && x0   < FXV) ? 1.0f : 0.0f;
            float vx1 = (x0+1 >= 0 && x0+1 < FXV) ? 1.0f : 0.0f;
            float vy0 = (y0   >= 0 && y0   < FZV) ? 1.0f : 0.0f;
            float vy1 = (y0+1 >= 0 && y0+1 < FZV) ? 1.0f : 0.0f;
            float w00 = (1.0f-wx)*(1.0f-wy)*vx0*vy0;
            float w10 = wx*(1.0f-wy)*vx1*vy0;
            float w01 = (1.0f-wx)*wy*vx0*vy1;
            float w11 = wx*wy*vx1*vy1;
            int xi0 = min(max(x0,   0), FXV-1), xi1 = min(max(x0+1, 0), FXV-1);
            int yi0 = min(max(y0,   0), FZV-1), yi1 = min(max(y0+1, 0), FZV-1);
            int o00 = xi0*FZV + yi0, o01 = xi0*FZV + yi1;
            int o10 = xi1*FZV + yi0, o11 = xi1*FZV + yi1;
            const float* p = img_feats + (size_t)b * (CCH*FXV*FZV);
            #pragma unroll
            for (int c = 0; c < CCH; c++) {
                const float* pc = p + c * (FXV*FZV);
                fsum[c] += w00*pc[o00] + w01*pc[o01] + w10*pc[o10] + w11*pc[o11];
            }
        }
        {
            float xf = v - 0.5f;
            float yf = u - 0.5f;
            float x0f = floorf(xf), y0f = floorf(yf);
            float wx = xf - x0f, wy = yf - y0f;
            int x0 = (int)x0f, y0 = (int)y0f;
            float vx0 = (x0   >= 0 && x0   < IMG_H) ? 1.0f : 0.0f;
            float vx1 = (x0+1 >= 0 && x0+1 < IMG_H) ? 1.0f : 0.0f;
            float vy0 = (y0   >= 0 && y0   < IMG_W) ? 1.0f : 0.0f;
            float vy1 = (y0+1 >= 0 && y0+1 < IMG_W) ? 1.0f : 0.0f;
            float w00 = (1.0f-wx)*(1.0f-wy)*vx0*vy0;
            float w10 = wx*(1.0f-wy)*vx1*vy0;
            float w01 = (1.0f-wx)*wy*vx0*vy1;
            float w11 = wx*wy*vx1*vy1;
            int xi0 = min(max(x0,   0), IMG_H-1), xi1 = min(max(x0+1, 0), IMG_H-1);
            int yi0 = min(max(y0,   0), IMG_W-1), yi1 = min(max(y0+1, 0), IMG_W-1);
            int o00 = xi0*IMG_W + yi0, o01 = xi0*IMG_W + yi1;
            int o10 = xi1*IMG_W + yi0, o11 = xi1*IMG_W + yi1;
            const float* pv = variances    + (size_t)b * (IMG_H*IMG_W);
            const float* pd = render_depth + (size_t)b * (IMG_H*IMG_W);
            vsum  += w00*pv[o00] + w01*pv[o01] + w10*pv[o10] + w11*pv[o11];
            ndsum += w00*pd[o00] + w01*pd[o01] + w10*pd[o10] + w11*pd[o11];
        }
    }

    float invd = 1.0f / (wsum + 1e-6f);
    #pragma unroll
    for (int c = 0; c < CCH; c++) out[(size_t)c * NVOX + n] = fsum[c] * invd;
    out[(size_t)CCH*NVOX + n]              = vsum  * invd;
    out[(size_t)CCH*NVOX + NVOX + n]       = zsum  * invd;
    out[(size_t)CCH*NVOX + 2*(size_t)NVOX + n] = ndsum * invd;
}

extern "C" void kernel_launch(void* const* d_in, const int* in_sizes, int n_in,
                              void* d_out, int out_size, void* d_ws, size_t ws_size,
                              hipStream_t stream) {
    const float* img_feats    = (const float*)d_in[0];
    const float* variances    = (const float*)d_in[1];
    const float* render_depth = (const float*)d_in[2];
    const float* coords       = (const float*)d_in[3];
    const float* Ps           = (const float*)d_in[4];
    const float* Ks           = (const float*)d_in[5];
    float* out = (float*)d_out;

    if (ws_size >= WS_NEED_BYTES) {
        float* feats_t = (float*)d_ws;
        float* vd_t    = feats_t + FEATS_T_ELEMS;
        {
            int total = NF + NV;
            hipLaunchKernelGGL(prep_all, dim3((total + 255) / 256), dim3(256), 0, stream,
                               img_feats, variances, render_depth, feats_t, vd_t);
        }
        hipLaunchKernelGGL(mvmap_fast, dim3(NVOX / 256), dim3(256), 0, stream,
                           feats_t, vd_t, coords, Ps, Ks, out);
    } else {
        hipLaunchKernelGGL(mvmap_main, dim3(NVOX / 256), dim3(256), 0, stream,
                           img_feats, variances, render_depth, coords, Ps, Ks, out);
    }
}

// Round 12
// 39.950 us; speedup vs baseline: 1.2710x; 1.0576x over previous
//
#include <hip/hip_runtime.h>
#include <math.h>

#define NCAMS 6
#define CCH   32
#define YY    8
#define XX    256
#define ZZ    256
#define NVOX  (YY*XX*ZZ)        // 524288
#define IMG_H 224
#define IMG_W 400
#define FXV   56
#define FZV   100

#define NF (NCAMS*FXV*FZV)          // 33600 feat pixels
#define NV (NCAMS*IMG_H*IMG_W)      // 537600 vd pixels
#define FEATS16_BYTES ((size_t)NF * CCH * 2)   // 2,150,400 B  bf16 channels-last
#define VD32_BYTES    ((size_t)NV * 4)         // 2,150,400 B  (var,dep) 2xbf16 in u32
#define WS_NEED_BYTES (FEATS16_BYTES + VD32_BYTES)

// round-to-nearest-even f32 -> bf16 (upper 16 bits)
__device__ __forceinline__ unsigned int bf16rn(float f) {
    unsigned int x = __float_as_uint(f);
    return (x + 0x7fffu + ((x >> 16) & 1u)) >> 16;
}
__device__ __forceinline__ float bf_lo(unsigned int u) {   // low bf16 -> f32
    return __uint_as_float(u << 16);
}
__device__ __forceinline__ float bf_hi(unsigned int u) {   // high bf16 -> f32
    return __uint_as_float(u & 0xffff0000u);
}

// ---------------- fused prep:
//   feats [6,32,56,100] f32 -> [6,56,100,32] bf16 (64B per pixel, ALL 32 channels)
//   var+dep -> [6,224,400] u32 (lo=var bf16, hi=dep bf16)
__global__ __launch_bounds__(256) void prep_all(
    const float* __restrict__ src_f, const float* __restrict__ var,
    const float* __restrict__ dep, unsigned short* __restrict__ dst_f,
    unsigned int* __restrict__ dst_vd)
{
    int t = blockIdx.x * 256 + threadIdx.x;
    if (t < NF) {
        int b = t / (FXV * FZV);
        int r = t - b * (FXV * FZV);
        unsigned int packed[16];               // 16 u32 = 32 bf16 channels (r11 bug: was 8)
        #pragma unroll
        for (int j = 0; j < 16; j++) {
            float c0 = src_f[(size_t)(b * CCH + 2*j + 0) * (FXV*FZV) + r];
            float c1 = src_f[(size_t)(b * CCH + 2*j + 1) * (FXV*FZV) + r];
            // channels 2j, 2j+1 -> lo, hi
            packed[j] = bf16rn(c0) | (bf16rn(c1) << 16);
        }
        uint4* d4 = (uint4*)(dst_f + (size_t)t * CCH);
        d4[0] = make_uint4(packed[0],  packed[1],  packed[2],  packed[3]);
        d4[1] = make_uint4(packed[4],  packed[5],  packed[6],  packed[7]);
        d4[2] = make_uint4(packed[8],  packed[9],  packed[10], packed[11]);
        d4[3] = make_uint4(packed[12], packed[13], packed[14], packed[15]);
    } else {
        int u = t - NF;
        if (u < NV) dst_vd[u] = bf16rn(var[u]) | (bf16rn(dep[u]) << 16);
    }
}

// ---- main: 256-thread blocks = 4 independent waves, wave = 64 voxels.
//      Phase1 lane=voxel (project + bf16 vd + aux). Phase2: two passes of 4
//      sub-rounds (8 lanes/voxel x 4 channels, bf16 uint2 taps = 1 line/tap-row)
//      -> per-wave 32x33 LDS transpose -> 128B-contiguous full-line f32 stores.
//      launch_bounds(256,4): cap 128 VGPR (cap 64 in r9 spilled -> +33MB WRITE).
__global__ __launch_bounds__(256, 4) void mvmap_fast(
    const unsigned short* __restrict__ feats16, // [6,56,100,32] bf16
    const unsigned int* __restrict__ vd32,      // [6,224,400] packed
    const float* __restrict__ coords,    // [1,524288,3]  (px, pz, h)
    const float* __restrict__ Ps,        // [6,4,4] cam2world
    const float* __restrict__ Ks,        // [6,3,3]
    float* __restrict__ out)
{
    __shared__ float4 sW2C[NCAMS][3];   // rows [i0 i1 i2 | t]
    __shared__ float4 sK[NCAMS][3];     // rows of K (w unused)
    __shared__ float  sT[4][32 * 33];   // per-wave half-tile transpose buffer

    if (threadIdx.x < NCAMS) {
        int b = threadIdx.x;
        const float* P = Ps + b * 16;
        float r00=P[0], r01=P[1], r02=P[2],  tx=P[3];
        float r10=P[4], r11=P[5], r12=P[6],  ty=P[7];
        float r20=P[8], r21=P[9], r22=P[10], tz=P[11];
        float det = r00*(r11*r22 - r12*r21)
                  - r01*(r10*r22 - r12*r20)
                  + r02*(r10*r21 - r11*r20);
        float id = 1.0f / det;
        float i00 =  (r11*r22 - r12*r21) * id;
        float i01 = -(r01*r22 - r02*r21) * id;
        float i02 =  (r01*r12 - r02*r11) * id;
        float i10 = -(r10*r22 - r12*r20) * id;
        float i11 =  (r00*r22 - r02*r20) * id;
        float i12 = -(r00*r12 - r02*r10) * id;
        float i20 =  (r10*r21 - r11*r20) * id;
        float i21 = -(r00*r21 - r01*r20) * id;
        float i22 =  (r00*r11 - r01*r10) * id;
        sW2C[b][0] = make_float4(i00, i01, i02, -(i00*tx + i01*ty + i02*tz));
        sW2C[b][1] = make_float4(i10, i11, i12, -(i10*tx + i11*ty + i12*tz));
        sW2C[b][2] = make_float4(i20, i21, i22, -(i20*tx + i21*ty + i22*tz));
        sK[b][0] = make_float4(Ks[b*9+0], Ks[b*9+1], Ks[b*9+2], 0.f);
        sK[b][1] = make_float4(Ks[b*9+3], Ks[b*9+4], Ks[b*9+5], 0.f);
        sK[b][2] = make_float4(Ks[b*9+6], Ks[b*9+7], Ks[b*9+8], 0.f);
    }
    __syncthreads();

    int wv   = threadIdx.x >> 6;             // wave within block (0..3)
    int lane = threadIdx.x & 63;             // lane within wave
    int n0   = blockIdx.x * 256 + wv * 64;   // wave's 64-voxel base
    int n    = n0 + lane;                    // this lane's voxel

    float px = coords[3*n + 0];
    float pz = coords[3*n + 1];
    float ph = coords[3*n + 2];

    // ---------------- phase 1: projection + mask, compact into slots (lane = voxel)
    float wsum = 0.0f, zsum = 0.0f;
    int   nvis = 0;
    float s_u[3] = {0.f, 0.f, 0.f};
    float s_v[3] = {0.f, 0.f, 0.f};
    int   s_b[3] = {0, 0, 0};

    #pragma unroll
    for (int b = 0; b < NCAMS; b++) {
        float4 r0 = sW2C[b][0], r1 = sW2C[b][1], r2 = sW2C[b][2];
        float cx = r0.x*px + r0.y*pz + r0.z*ph + r0.w;
        float cy = r1.x*px + r1.y*pz + r1.z*ph + r1.w;
        float cz = r2.x*px + r2.y*pz + r2.z*ph + r2.w;
        float4 k0 = sK[b][0], k1 = sK[b][1], k2 = sK[b][2];
        float u0 = k0.x*cx + k0.y*cy + k0.z*cz;
        float v0 = k1.x*cx + k1.y*cy + k1.z*cz;
        float zc = k2.x*cx + k2.y*cy + k2.z*cz;
        float zsafe = (fabsf(zc) < 1e-6f) ? 1e-6f : zc;
        float u = u0 / zsafe;                 // exact IEEE divide (mask bit-identity)
        float v = v0 / zsafe;
        bool mask = (zc > 1e-3f) && (u >= 0.0f) && (u < (float)IMG_W)
                                 && (v >= 0.0f) && (v < (float)IMG_H);
        wsum += mask ? 1.0f : 0.0f;
        zsum += mask ? zc : 0.0f;
        bool c0 = mask && (nvis == 0);
        bool c1 = mask && (nvis == 1);
        bool c2 = mask && (nvis == 2);        // geometrically dead (HFOV 77 < 120), defensive
        s_u[0] = c0 ? u : s_u[0];  s_v[0] = c0 ? v : s_v[0];  s_b[0] = c0 ? b : s_b[0];
        s_u[1] = c1 ? u : s_u[1];  s_v[1] = c1 ? v : s_v[1];  s_b[1] = c1 ? b : s_b[1];
        s_u[2] = c2 ? u : s_u[2];  s_v[2] = c2 ? v : s_v[2];  s_b[2] = c2 ? b : s_b[2];
        nvis += mask ? 1 : 0;
    }
    float invd = 1.0f / (wsum + 1e-6f);

    // ---------------- phase 1b: variance + depth bilinear (lane = voxel, packed bf16)
    float vsum = 0.0f, ndsum = 0.0f;
    #pragma unroll
    for (int it = 0; it < 3; it++) {
        if (it < nvis) {
            float u = s_u[it], v = s_v[it];
            int   b = s_b[it];
            float xf = v - 0.5f;
            float yf = u - 0.5f;
            float x0f = floorf(xf), y0f = floorf(yf);
            float wx = xf - x0f, wy = yf - y0f;
            int x0 = (int)x0f, y0 = (int)y0f;
            float vx0 = (x0   >= 0 && x0   < IMG_H) ? 1.0f : 0.0f;
            float vx1 = (x0+1 >= 0 && x0+1 < IMG_H) ? 1.0f : 0.0f;
            float vy0 = (y0   >= 0 && y0   < IMG_W) ? 1.0f : 0.0f;
            float vy1 = (y0+1 >= 0 && y0+1 < IMG_W) ? 1.0f : 0.0f;
            float w00 = (1.0f-wx)*(1.0f-wy)*vx0*vy0;
            float w10 = wx*(1.0f-wy)*vx1*vy0;
            float w01 = (1.0f-wx)*wy*vx0*vy1;
            float w11 = wx*wy*vx1*vy1;
            int xi0 = min(max(x0,   0), IMG_H-1), xi1 = min(max(x0+1, 0), IMG_H-1);
            int yi0 = min(max(y0,   0), IMG_W-1), yi1 = min(max(y0+1, 0), IMG_W-1);
            const unsigned int* pv = vd32 + (size_t)b * (IMG_H*IMG_W);
            unsigned int t00 = pv[xi0*IMG_W + yi0], t01 = pv[xi0*IMG_W + yi1];
            unsigned int t10 = pv[xi1*IMG_W + yi0], t11 = pv[xi1*IMG_W + yi1];
            vsum  += w00*bf_lo(t00) + w01*bf_lo(t01) + w10*bf_lo(t10) + w11*bf_lo(t11);
            ndsum += w00*bf_hi(t00) + w01*bf_hi(t01) + w10*bf_hi(t10) + w11*bf_hi(t11);
        }
    }
    __builtin_nontemporal_store(vsum  * invd, &out[(size_t)CCH*NVOX + n]);
    __builtin_nontemporal_store(zsum  * invd, &out[(size_t)CCH*NVOX + NVOX + n]);
    __builtin_nontemporal_store(ndsum * invd, &out[(size_t)CCH*NVOX + 2*(size_t)NVOX + n]);

    // ---------------- phase 2: two passes x 4 sub-rounds; 8 lanes/voxel x 4 channels
    //                  taps are bf16 uint2 (8B/lane) -> one 64B line per tap-row
    int cg = lane & 7;        // channel group: channels 4*cg .. 4*cg+3
    int vg = lane >> 3;       // voxel offset within each 8-voxel sub-round

    #pragma unroll
    for (int p = 0; p < 2; p++) {
        #pragma unroll
        for (int sr = 0; sr < 4; sr++) {
            int s   = 4*p + sr;
            int src = 8*s + vg;                 // lane owning this voxel's projection

            // ---- HOISTED broadcasts: executed by ALL lanes (defined behavior) ----
            int   nv  = __shfl(nvis, src);
            float iv  = __shfl(invd, src);
            float uu0 = __shfl(s_u[0], src), vv0 = __shfl(s_v[0], src);
            float uu1 = __shfl(s_u[1], src), vv1 = __shfl(s_v[1], src);
            float uu2 = __shfl(s_u[2], src), vv2 = __shfl(s_v[2], src);
            int   bb0 = __shfl(s_b[0], src);
            int   bb1 = __shfl(s_b[1], src);
            int   bb2 = __shfl(s_b[2], src);
            float uu[3] = {uu0, uu1, uu2};
            float vv[3] = {vv0, vv1, vv2};
            int   bb[3] = {bb0, bb1, bb2};

            float ax = 0.f, ay = 0.f, az = 0.f, aw = 0.f;
            #pragma unroll
            for (int it = 0; it < 3; it++) {
                if (it < nv) {
                    float u = uu[it], v = vv[it];
                    int   b = bb[it];
                    float xf = v * 0.25f - 0.5f;      // width dim (56)
                    float yf = u * 0.25f - 0.5f;      // height dim (100)
                    float x0f = floorf(xf), y0f = floorf(yf);
                    float wx = xf - x0f, wy = yf - y0f;
                    int x0 = (int)x0f, y0 = (int)y0f;
                    float vx0 = (x0   >= 0 && x0   < FXV) ? 1.0f : 0.0f;
                    float vx1 = (x0+1 >= 0 && x0+1 < FXV) ? 1.0f : 0.0f;
                    float vy0 = (y0   >= 0 && y0   < FZV) ? 1.0f : 0.0f;
                    float vy1 = (y0+1 >= 0 && y0+1 < FZV) ? 1.0f : 0.0f;
                    float w00 = (1.0f-wx)*(1.0f-wy)*vx0*vy0;
                    float w10 = wx*(1.0f-wy)*vx1*vy0;
                    float w01 = (1.0f-wx)*wy*vx0*vy1;
                    float w11 = wx*wy*vx1*vy1;
                    int xi0 = min(max(x0,   0), FXV-1), xi1 = min(max(x0+1, 0), FXV-1);
                    int yi0 = min(max(y0,   0), FZV-1), yi1 = min(max(y0+1, 0), FZV-1);
                    const unsigned short* base =
                        feats16 + (size_t)b * (FXV*FZV*CCH) + cg * 4;
                    uint2 a  = *(const uint2*)(base + (size_t)(xi0*FZV + yi0)*CCH);
                    uint2 b2 = *(const uint2*)(base + (size_t)(xi0*FZV + yi1)*CCH);
                    uint2 c2 = *(const uint2*)(base + (size_t)(xi1*FZV + yi0)*CCH);
                    uint2 d2 = *(const uint2*)(base + (size_t)(xi1*FZV + yi1)*CCH);
                    ax += w00*bf_lo(a.x) + w01*bf_lo(b2.x) + w10*bf_lo(c2.x) + w11*bf_lo(d2.x);
                    ay += w00*bf_hi(a.x) + w01*bf_hi(b2.x) + w10*bf_hi(c2.x) + w11*bf_hi(d2.x);
                    az += w00*bf_lo(a.y) + w01*bf_lo(b2.y) + w10*bf_lo(c2.y) + w11*bf_lo(d2.y);
                    aw += w00*bf_hi(a.y) + w01*bf_hi(b2.y) + w10*bf_hi(c2.y) + w11*bf_hi(d2.y);
                }
            }
            // local voxel row within this pass's 32-voxel half-tile
            float* pt = &sT[wv][(8*sr + vg) * 33 + cg * 4];
            pt[0] = ax * iv;
            pt[1] = ay * iv;
            pt[2] = az * iv;
            pt[3] = aw * iv;
        }
        __syncthreads();

        // ---- transpose-store: 16 instrs, each 2 channels x 32 voxels (2x128B lines)
        int row  = lane & 31;                    // voxel within half-tile
        int half = lane >> 5;                    // 0: even channel, 1: odd channel
        int vn   = n0 + 32*p + row;
        #pragma unroll
        for (int i = 0; i < 16; i++) {
            int c = 2*i + half;
            float val = sT[wv][row * 33 + c];
            __builtin_nontemporal_store(val, &out[(size_t)c * NVOX + vn]);
        }
        __syncthreads();
    }
}

// ---------------- fallback (original layouts, one thread per voxel) --------------
__global__ __launch_bounds__(256) void mvmap_main(
    const float* __restrict__ img_feats,
    const float* __restrict__ variances,
    const float* __restrict__ render_depth,
    const float* __restrict__ coords,
    const float* __restrict__ Ps,
    const float* __restrict__ Ks,
    float* __restrict__ out)
{
    __shared__ float sW2C[NCAMS][12];
    __shared__ float sK[NCAMS][9];

    if (threadIdx.x < NCAMS) {
        int b = threadIdx.x;
        const float* P = Ps + b * 16;
        float r00=P[0], r01=P[1], r02=P[2],  tx=P[3];
        float r10=P[4], r11=P[5], r12=P[6],  ty=P[7];
        float r20=P[8], r21=P[9], r22=P[10], tz=P[11];
        float det = r00*(r11*r22 - r12*r21)
                  - r01*(r10*r22 - r12*r20)
                  + r02*(r10*r21 - r11*r20);
        float id = 1.0f / det;
        float i00 =  (r11*r22 - r12*r21) * id;
        float i01 = -(r01*r22 - r02*r21) * id;
        float i02 =  (r01*r12 - r02*r11) * id;
        float i10 = -(r10*r22 - r12*r20) * id;
        float i11 =  (r00*r22 - r02*r20) * id;
        float i12 = -(r00*r12 - r02*r10) * id;
        float i20 =  (r10*r21 - r11*r20) * id;
        float i21 = -(r00*r21 - r01*r20) * id;
        float i22 =  (r00*r11 - r01*r10) * id;
        sW2C[b][0]=i00; sW2C[b][1]=i01; sW2C[b][2] =i02; sW2C[b][3] =-(i00*tx + i01*ty + i02*tz);
        sW2C[b][4]=i10; sW2C[b][5]=i11; sW2C[b][6] =i12; sW2C[b][7] =-(i10*tx + i11*ty + i12*tz);
        sW2C[b][8]=i20; sW2C[b][9]=i21; sW2C[b][10]=i22; sW2C[b][11]=-(i20*tx + i21*ty + i22*tz);
        #pragma unroll
        for (int jj = 0; jj < 9; jj++) sK[b][jj] = Ks[b*9 + jj];
    }
    __syncthreads();

    int n = blockIdx.x * blockDim.x + threadIdx.x;
    if (n >= NVOX) return;

    float px = coords[3*n + 0];
    float pz = coords[3*n + 1];
    float ph = coords[3*n + 2];

    float fsum[CCH];
    #pragma unroll
    for (int c = 0; c < CCH; c++) fsum[c] = 0.0f;
    float wsum = 0.0f, vsum = 0.0f, ndsum = 0.0f, zsum = 0.0f;

    for (int b = 0; b < NCAMS; b++) {
        float cx = sW2C[b][0]*px + sW2C[b][1]*pz + sW2C[b][2] *ph + sW2C[b][3];
        float cy = sW2C[b][4]*px + sW2C[b][5]*pz + sW2C[b][6] *ph + sW2C[b][7];
        float cz = sW2C[b][8]*px + sW2C[b][9]*pz + sW2C[b][10]*ph + sW2C[b][11];
        float u0 = sK[b][0]*cx + sK[b][1]*cy + sK[b][2]*cz;
        float v0 = sK[b][3]*cx + sK[b][4]*cy + sK[b][5]*cz;
        float zc = sK[b][6]*cx + sK[b][7]*cy + sK[b][8]*cz;
        float zsafe = (fabsf(zc) < 1e-6f) ? 1e-6f : zc;
        float u = u0 / zsafe;
        float v = v0 / zsafe;
        bool mask = (zc > 1e-3f) && (u >= 0.0f) && (u < (float)IMG_W)
                                 && (v >= 0.0f) && (v < (float)IMG_H);
        if (!mask) continue;

        wsum += 1.0f;
        zsum += zc;
        {
            float xf = v * 0.25f - 0.5f;
            float yf = u * 0.25f - 0.5f;
            float x0f = floorf(xf), y0f = floorf(yf);
            float wx = xf - x0f, wy = yf - y0f;
            int x0 = (int)x0f, y0 = (int)y0f;
            float vx0 = (x0   >= 0 && x0   < FXV) ? 1.0f : 0.0f;
            float vx1 = (x0+1 >= 0 && x0+1 < FXV) ? 1.0f : 0.0f;
            float vy0 = (y0   >= 0 && y0   < FZV) ? 1.0f : 0.0f;
            float vy1 = (y0+1 >= 0 && y0+1 < FZV) ? 1.0f : 0.0f;
            float w00 = (1.0f-wx)*(1.0f-wy)*vx0*vy0;
            float w10 = wx*(1.0f-wy)*vx1*vy0;
            float w01 = (1.0f-wx)*wy*vx0*vy1;
            float w11 = wx*wy*vx1*vy1;
            int xi0 = min(max(x0,   0), FXV-1), xi1 = min(max(x0+1, 0), FXV-1);
            int yi0 = min(max(y0,   0), FZV-1), yi1 = min(max(y0+1, 0), FZV-1);
            int o00 = xi0*FZV + yi0, o01 = xi0*FZV + yi1;
            int o10 = xi1*FZV + yi0, o11 = xi1*FZV + yi1;
            const float* p = img_feats + (size_t)b * (CCH*FXV*FZV);
            #pragma unroll
            for (int c = 0; c < CCH; c++) {
                const float* pc = p + c * (FXV*FZV);
                fsum[c] += w00*pc[o00] + w01*pc[o01] + w10*pc[o10] + w11*pc[o11];
            }
        }
        {
            float xf = v - 0.5f;
            float yf = u - 0.5f;
            float x0f = floorf(xf), y0f = floorf(yf);
            float wx = xf - x0f, wy = yf - y0f;
            int x0 = (int)x0f, y0 = (int)y0f;
            float vx0 = (x0   >= 0 && x0   < IMG_H) ? 1.0f : 0.0f;
            float vx1 = (x0+1 >= 0 && x0+1 < IMG_H) ? 1.0f : 0.0f;
            float vy0 = (y0   >= 0 && y0   < IMG_W) ? 1.0f : 0.0f;
            float vy1 = (y0+1 >= 0 && y0+1 < IMG_W) ? 1.0f : 0.0f;
            float w00 = (1.0f-wx)*(1.0f-wy)*vx0*vy0;
            float w10 = wx*(1.0f-wy)*vx1*vy0;
            float w01 = (1.0f-wx)*wy*vx0*vy1;
            float w11 = wx*wy*vx1*vy1;
            int xi0 = min(max(x0,   0), IMG_H-1), xi1 = min(max(x0+1, 0), IMG_H-1);
            int yi0 = min(max(y0,   0), IMG_W-1), yi1 = min(max(y0+1, 0), IMG_W-1);
            int o00 = xi0*IMG_W + yi0, o01 = xi0*IMG_W + yi1;
            int o10 = xi1*IMG_W + yi0, o11 = xi1*IMG_W + yi1;
            const float* pv = variances    + (size_t)b * (IMG_H*IMG_W);
            const float* pd = render_depth + (size_t)b * (IMG_H*IMG_W);
            vsum  += w00*pv[o00] + w01*pv[o01] + w10*pv[o10] + w11*pv[o11];
            ndsum += w00*pd[o00] + w01*pd[o01] + w10*pd[o10] + w11*pd[o11];
        }
    }

    float invd = 1.0f / (wsum + 1e-6f);
    #pragma unroll
    for (int c = 0; c < CCH; c++) out[(size_t)c * NVOX + n] = fsum[c] * invd;
    out[(size_t)CCH*NVOX + n]              = vsum  * invd;
    out[(size_t)CCH*NVOX + NVOX + n]       = zsum  * invd;
    out[(size_t)CCH*NVOX + 2*(size_t)NVOX + n] = ndsum * invd;
}

extern "C" void kernel_launch(void* const* d_in, const int* in_sizes, int n_in,
                              void* d_out, int out_size, void* d_ws, size_t ws_size,
                              hipStream_t stream) {
    const float* img_feats    = (const float*)d_in[0];
    const float* variances    = (const float*)d_in[1];
    const float* render_depth = (const float*)d_in[2];
    const float* coords       = (const float*)d_in[3];
    const float* Ps           = (const float*)d_in[4];
    const float* Ks           = (const float*)d_in[5];
    float* out = (float*)d_out;

    if (ws_size >= WS_NEED_BYTES) {
        unsigned short* feats16 = (unsigned short*)d_ws;
        unsigned int*   vd32    = (unsigned int*)((char*)d_ws + FEATS16_BYTES);
        {
            int total = NF + NV;
            hipLaunchKernelGGL(prep_all, dim3((total + 255) / 256), dim3(256), 0, stream,
                               img_feats, variances, render_depth, feats16, vd32);
        }
        hipLaunchKernelGGL(mvmap_fast, dim3(NVOX / 256), dim3(256), 0, stream,
                           feats16, vd32, coords, Ps, Ks, out);
    } else {
        hipLaunchKernelGGL(mvmap_main, dim3(NVOX / 256), dim3(256), 0, stream,
                           img_feats, variances, render_depth, coords, Ps, Ks, out);
    }
}